// Round 1
// baseline (3446.059 us; speedup 1.0000x reference)
//
#include <hip/hip_runtime.h>
#include <math.h>

// ---------------------------------------------------------------------------
// RelFuseNet forward, fp32 baseline.
// Pipeline:
//   y1l = concat(h_v,h_t,h_tab) @ W1l            (GEMM, multi-ptr A)
//   y1r = concat(...) @ W1r
//   agg1 = segment_sum(y1l[src], dst)            (atomics)
//   h_g1 = relu(agg1*inv_cnt + b1g + y1r)
//   y2l = h_g1 @ W2l ; y2r = h_g1 @ W2r
//   agg2 = segment_sum(y2l[src], dst)
//   h_g  = l2norm(agg2*inv_cnt + b2g + y2r)
//   z_sh = h_g@Wsh+bsh ; z_t = h_t@Wst+bst ; z_tab = h_tab@Wstab+bstab
//   hidden = relu([z_sh|z_t|z_tab|h_g] @ Wc1 + bc1)   (multi-ptr A)
//   logits = hidden @ Wc2 + bc2
// ---------------------------------------------------------------------------

// ---- 64x64x16 fp32 tile GEMM; A optionally concat of 4 [M,128] segments ----
__global__ __launch_bounds__(256) void gemm_tile(
    const float* __restrict__ A0, const float* __restrict__ A1,
    const float* __restrict__ A2, const float* __restrict__ A3,
    const float* __restrict__ B, const float* __restrict__ bias,
    float* __restrict__ C, int M, int K, int NN, int multi, int relu)
{
    __shared__ __align__(16) float As[16][68];
    __shared__ __align__(16) float Bs[16][68];
    const int m0 = blockIdx.x * 64;
    const int n0 = blockIdx.y * 64;
    const int tid = threadIdx.x;
    const int tm = tid >> 4;   // 0..15
    const int tn = tid & 15;   // 0..15
    float acc[4][4] = {};

    for (int k0 = 0; k0 < K; k0 += 16) {
        const float* Aseg; int lda, kbase;
        if (multi) {
            int seg = k0 >> 7;
            Aseg = (seg == 0) ? A0 : (seg == 1) ? A1 : (seg == 2) ? A2 : A3;
            lda = 128; kbase = k0 & 127;
        } else {
            Aseg = A0; lda = K; kbase = k0;
        }
        // stage A tile (64 rows x 16 k), stored k-major
        #pragma unroll
        for (int p = 0; p < 4; ++p) {
            int r  = p * 16 + (tid >> 4);
            int kk = tid & 15;
            int row = m0 + r;
            float v = (row < M) ? Aseg[(size_t)row * lda + kbase + kk] : 0.0f;
            As[kk][r] = v;
        }
        // stage B tile (16 k x 64 n)
        #pragma unroll
        for (int p = 0; p < 4; ++p) {
            int kk = p * 4 + (tid >> 6);
            int nn = tid & 63;
            Bs[kk][nn] = B[(size_t)(k0 + kk) * NN + n0 + nn];
        }
        __syncthreads();
        #pragma unroll
        for (int kk = 0; kk < 16; ++kk) {
            const float4 a4 = *(const float4*)&As[kk][tm * 4];
            const float4 b4 = *(const float4*)&Bs[kk][tn * 4];
            const float a[4] = {a4.x, a4.y, a4.z, a4.w};
            const float b[4] = {b4.x, b4.y, b4.z, b4.w};
            #pragma unroll
            for (int i = 0; i < 4; ++i)
                #pragma unroll
                for (int j = 0; j < 4; ++j)
                    acc[i][j] += a[i] * b[j];
        }
        __syncthreads();
    }
    #pragma unroll
    for (int i = 0; i < 4; ++i) {
        int row = m0 + tm * 4 + i;
        if (row < M) {
            #pragma unroll
            for (int j = 0; j < 4; ++j) {
                int col = n0 + tn * 4 + j;
                float v = acc[i][j];
                if (bias) v += bias[col];
                if (relu) v = fmaxf(v, 0.0f);
                C[(size_t)row * NN + col] = v;
            }
        }
    }
}

// ---- edge degree count ----
__global__ void count_edges(const int* __restrict__ dst, float* __restrict__ cnt, int E)
{
    int e = blockIdx.x * blockDim.x + threadIdx.x;
    if (e < E) atomicAdd(&cnt[dst[e]], 1.0f);
}

__global__ void inv_count(float* __restrict__ cnt, int n)
{
    int i = blockIdx.x * blockDim.x + threadIdx.x;
    if (i < n) cnt[i] = 1.0f / fmaxf(cnt[i], 1.0f);
}

// ---- segment-sum of y[src] into agg[dst]; D = 4<<logc floats per row ----
__global__ void aggregate(const float* __restrict__ y, const int* __restrict__ src,
                          const int* __restrict__ dst, float* __restrict__ agg,
                          int E, int logc)
{
    long long t = (long long)blockIdx.x * blockDim.x + threadIdx.x;
    int e = (int)(t >> logc);
    if (e >= E) return;
    int c = (int)(t & ((1 << logc) - 1)) << 2;
    int D = 4 << logc;
    const float4 v = *(const float4*)(y + (size_t)src[e] * D + c);
    float* p = agg + (size_t)dst[e] * D + c;
    atomicAdd(p + 0, v.x);
    atomicAdd(p + 1, v.y);
    atomicAdd(p + 2, v.z);
    atomicAdd(p + 3, v.w);
}

// ---- h_g1 = relu(agg*inv + b + yr), D=256 ----
__global__ void finish1(const float* __restrict__ agg, const float* __restrict__ yr,
                        const float* __restrict__ inv, const float* __restrict__ b,
                        float* __restrict__ out, int total4)
{
    int t = blockIdx.x * blockDim.x + threadIdx.x;
    if (t >= total4) return;
    int row = t >> 6;
    int c4  = t & 63;
    float4 a = ((const float4*)agg)[t];
    float4 y = ((const float4*)yr)[t];
    float4 bb = ((const float4*)b)[c4];
    float s = inv[row];
    float4 o;
    o.x = fmaxf(a.x * s + bb.x + y.x, 0.0f);
    o.y = fmaxf(a.y * s + bb.y + y.y, 0.0f);
    o.z = fmaxf(a.z * s + bb.z + y.z, 0.0f);
    o.w = fmaxf(a.w * s + bb.w + y.w, 0.0f);
    ((float4*)out)[t] = o;
}

// ---- h_g = l2norm(agg*inv + b + yr), D=128; one wave per row ----
__global__ void finish2_norm(const float* __restrict__ agg, const float* __restrict__ yr,
                             const float* __restrict__ inv, const float* __restrict__ b,
                             float* __restrict__ out, int N)
{
    int lane = threadIdx.x & 63;
    int row = blockIdx.x * 4 + (threadIdx.x >> 6);
    if (row >= N) return;
    float s = inv[row];
    float2 a = ((const float2*)(agg + (size_t)row * 128))[lane];
    float2 y = ((const float2*)(yr + (size_t)row * 128))[lane];
    float2 bb = ((const float2*)b)[lane];
    float2 h;
    h.x = a.x * s + bb.x + y.x;
    h.y = a.y * s + bb.y + y.y;
    float ss = h.x * h.x + h.y * h.y;
    #pragma unroll
    for (int o = 32; o; o >>= 1) ss += __shfl_xor(ss, o);
    float sc = 1.0f / fmaxf(sqrtf(ss), 1e-12f);
    ((float2*)(out + (size_t)row * 128))[lane] = make_float2(h.x * sc, h.y * sc);
}

// ---- logits = hidden[N,256] @ Wc2[256,14] + bc2 ----
__global__ __launch_bounds__(256) void logits_kernel(
    const float* __restrict__ hidden, const float* __restrict__ W,
    const float* __restrict__ b, float* __restrict__ out, int N)
{
    __shared__ float Ws[256 * 14];
    __shared__ float bs[14];
    for (int i = threadIdx.x; i < 256 * 14; i += 256) Ws[i] = W[i];
    if (threadIdx.x < 14) bs[threadIdx.x] = b[threadIdx.x];
    __syncthreads();
    int c = threadIdx.x & 15;
    int r = threadIdx.x >> 4;
    int row = blockIdx.x * 16 + r;
    if (row >= N || c >= 14) return;
    const float* h = hidden + (size_t)row * 256;
    float acc = 0.0f;
    #pragma unroll 4
    for (int k4 = 0; k4 < 64; ++k4) {
        float4 hv = ((const float4*)h)[k4];
        acc += hv.x * Ws[(k4 * 4 + 0) * 14 + c];
        acc += hv.y * Ws[(k4 * 4 + 1) * 14 + c];
        acc += hv.z * Ws[(k4 * 4 + 2) * 14 + c];
        acc += hv.w * Ws[(k4 * 4 + 3) * 14 + c];
    }
    out[(size_t)row * 14 + c] = acc + bs[c];
}

extern "C" void kernel_launch(void* const* d_in, const int* in_sizes, int n_in,
                              void* d_out, int out_size, void* d_ws, size_t ws_size,
                              hipStream_t stream)
{
    const float* h_v   = (const float*)d_in[0];
    const float* h_t   = (const float*)d_in[1];
    const float* h_tab = (const float*)d_in[2];
    const int*   eidx  = (const int*)d_in[3];
    const float* W1l = (const float*)d_in[4];
    const float* W1r = (const float*)d_in[5];
    const float* b1g = (const float*)d_in[6];
    const float* W2l = (const float*)d_in[7];
    const float* W2r = (const float*)d_in[8];
    const float* b2g = (const float*)d_in[9];
    const float* Wsh = (const float*)d_in[10];
    const float* bsh = (const float*)d_in[11];
    const float* Wst = (const float*)d_in[12];
    const float* bst = (const float*)d_in[13];
    const float* Wstab = (const float*)d_in[14];
    const float* bstab = (const float*)d_in[15];
    const float* Wc1 = (const float*)d_in[16];
    const float* bc1 = (const float*)d_in[17];
    const float* Wc2 = (const float*)d_in[18];
    const float* bc2 = (const float*)d_in[19];

    const int N = in_sizes[0] / 128;      // 50000
    const int E = in_sizes[3] / 2;        // 500000
    const int* src = eidx;
    const int* dst = eidx + E;

    // workspace layout (floats)
    float* ws = (float*)d_ws;
    float* invc = ws;                                  // [N] cnt -> inv
    float* bufA = ws + 65536;                          // [N*256]
    float* bufB = bufA + (size_t)N * 256;              // [N*256]
    float* bufC = bufB + (size_t)N * 256;              // [N*256]
    // lifetimes:
    //  bufA: y1l -> h_g1 -> h_g (first N*128)
    //  bufB: y1r -> agg2 (first N*128)
    //  bufC: agg1 -> {y2l | y2r} -> hidden

    float* out    = (float*)d_out;
    float* logits = out;
    float* z_sh   = out + (size_t)N * 14;
    float* z_t    = z_sh + (size_t)N * 128;
    float* z_tab  = z_t + (size_t)N * 128;

    const int gx = (N + 63) / 64;  // 782

    // degree counts
    hipMemsetAsync(invc, 0, (size_t)N * 4, stream);
    count_edges<<<(E + 255) / 256, 256, 0, stream>>>(dst, invc, E);
    inv_count<<<(N + 255) / 256, 256, 0, stream>>>(invc, N);

    // conv1 GEMMs: [N,384] x [384,256]
    gemm_tile<<<dim3(gx, 4), 256, 0, stream>>>(h_v, h_t, h_tab, nullptr,
        W1l, nullptr, bufA, N, 384, 256, 1, 0);
    gemm_tile<<<dim3(gx, 4), 256, 0, stream>>>(h_v, h_t, h_tab, nullptr,
        W1r, nullptr, bufB, N, 384, 256, 1, 0);

    // conv1 aggregation + epilogue
    hipMemsetAsync(bufC, 0, (size_t)N * 256 * 4, stream);
    {
        long long tot = (long long)E * 64;
        int blocks = (int)((tot + 255) / 256);
        aggregate<<<blocks, 256, 0, stream>>>(bufA, src, dst, bufC, E, 6);
    }
    finish1<<<(N * 64 + 255) / 256, 256, 0, stream>>>(bufC, bufB, invc, b1g, bufA, N * 64);

    // conv2 GEMMs: [N,256] x [256,128]
    float* y2l = bufC;
    float* y2r = bufC + (size_t)N * 128;
    gemm_tile<<<dim3(gx, 2), 256, 0, stream>>>(bufA, nullptr, nullptr, nullptr,
        W2l, nullptr, y2l, N, 256, 128, 0, 0);
    gemm_tile<<<dim3(gx, 2), 256, 0, stream>>>(bufA, nullptr, nullptr, nullptr,
        W2r, nullptr, y2r, N, 256, 128, 0, 0);

    // conv2 aggregation + normalize epilogue
    float* agg2 = bufB;
    hipMemsetAsync(agg2, 0, (size_t)N * 128 * 4, stream);
    {
        long long tot = (long long)E * 32;
        int blocks = (int)((tot + 255) / 256);
        aggregate<<<blocks, 256, 0, stream>>>(y2l, src, dst, agg2, E, 5);
    }
    float* hg = bufA;  // [N,128]
    finish2_norm<<<(N + 3) / 4, 256, 0, stream>>>(agg2, y2r, invc, b2g, hg, N);

    // projections -> d_out
    gemm_tile<<<dim3(gx, 2), 256, 0, stream>>>(hg, nullptr, nullptr, nullptr,
        Wsh, bsh, z_sh, N, 128, 128, 0, 0);
    gemm_tile<<<dim3(gx, 2), 256, 0, stream>>>(h_t, nullptr, nullptr, nullptr,
        Wst, bst, z_t, N, 128, 128, 0, 0);
    gemm_tile<<<dim3(gx, 2), 256, 0, stream>>>(h_tab, nullptr, nullptr, nullptr,
        Wstab, bstab, z_tab, N, 128, 128, 0, 0);

    // classifier layer 1: [N,512] x [512,256], relu
    float* hidden = bufC;
    gemm_tile<<<dim3(gx, 4), 256, 0, stream>>>(z_sh, z_t, z_tab, hg,
        Wc1, bc1, hidden, N, 512, 256, 1, 1);

    // classifier layer 2: [N,256] x [256,14]
    logits_kernel<<<(N + 15) / 16, 256, 0, stream>>>(hidden, Wc2, bc2, logits, N);
}

// Round 2
// 1110.754 us; speedup vs baseline: 3.1024x; 3.1024x over previous
//
#include <hip/hip_runtime.h>
#include <math.h>

// ---------------------------------------------------------------------------
// RelFuseNet forward. Round 2: CSR-gather aggregation (no fp32 atomics),
// fused epilogues. GEMMs still fp32 tile (measure them this round).
// ---------------------------------------------------------------------------

// ---- 64x64x16 fp32 tile GEMM; A optionally concat of 4 [M,128] segments ----
__global__ __launch_bounds__(256) void gemm_tile(
    const float* __restrict__ A0, const float* __restrict__ A1,
    const float* __restrict__ A2, const float* __restrict__ A3,
    const float* __restrict__ B, const float* __restrict__ bias,
    float* __restrict__ C, int M, int K, int NN, int multi, int relu)
{
    __shared__ __align__(16) float As[16][68];
    __shared__ __align__(16) float Bs[16][68];
    const int m0 = blockIdx.x * 64;
    const int n0 = blockIdx.y * 64;
    const int tid = threadIdx.x;
    const int tm = tid >> 4;   // 0..15
    const int tn = tid & 15;   // 0..15
    float acc[4][4] = {};

    for (int k0 = 0; k0 < K; k0 += 16) {
        const float* Aseg; int lda, kbase;
        if (multi) {
            int seg = k0 >> 7;
            Aseg = (seg == 0) ? A0 : (seg == 1) ? A1 : (seg == 2) ? A2 : A3;
            lda = 128; kbase = k0 & 127;
        } else {
            Aseg = A0; lda = K; kbase = k0;
        }
        #pragma unroll
        for (int p = 0; p < 4; ++p) {
            int r  = p * 16 + (tid >> 4);
            int kk = tid & 15;
            int row = m0 + r;
            float v = (row < M) ? Aseg[(size_t)row * lda + kbase + kk] : 0.0f;
            As[kk][r] = v;
        }
        #pragma unroll
        for (int p = 0; p < 4; ++p) {
            int kk = p * 4 + (tid >> 6);
            int nn = tid & 63;
            Bs[kk][nn] = B[(size_t)(k0 + kk) * NN + n0 + nn];
        }
        __syncthreads();
        #pragma unroll
        for (int kk = 0; kk < 16; ++kk) {
            const float4 a4 = *(const float4*)&As[kk][tm * 4];
            const float4 b4 = *(const float4*)&Bs[kk][tn * 4];
            const float a[4] = {a4.x, a4.y, a4.z, a4.w};
            const float b[4] = {b4.x, b4.y, b4.z, b4.w};
            #pragma unroll
            for (int i = 0; i < 4; ++i)
                #pragma unroll
                for (int j = 0; j < 4; ++j)
                    acc[i][j] += a[i] * b[j];
        }
        __syncthreads();
    }
    #pragma unroll
    for (int i = 0; i < 4; ++i) {
        int row = m0 + tm * 4 + i;
        if (row < M) {
            #pragma unroll
            for (int j = 0; j < 4; ++j) {
                int col = n0 + tn * 4 + j;
                float v = acc[i][j];
                if (bias) v += bias[col];
                if (relu) v = fmaxf(v, 0.0f);
                C[(size_t)row * NN + col] = v;
            }
        }
    }
}

// ---- CSR build ----
__global__ void count_deg(const int* __restrict__ dst, int* __restrict__ deg, int E)
{
    int e = blockIdx.x * blockDim.x + threadIdx.x;
    if (e < E) atomicAdd(&deg[dst[e]], 1);
}

// single-block chunked inclusive scan -> exclusive offsets + cursor copy
__global__ __launch_bounds__(1024) void scan_offsets(
    const int* __restrict__ deg, int* __restrict__ off,
    int* __restrict__ cursor, int N)
{
    __shared__ int buf[1024];
    __shared__ int carry_s;
    if (threadIdx.x == 0) carry_s = 0;
    __syncthreads();
    for (int base = 0; base < N; base += 1024) {
        int i = base + threadIdx.x;
        int v = (i < N) ? deg[i] : 0;
        buf[threadIdx.x] = v;
        __syncthreads();
        #pragma unroll
        for (int o = 1; o < 1024; o <<= 1) {
            int t = (threadIdx.x >= o) ? buf[threadIdx.x - o] : 0;
            __syncthreads();
            buf[threadIdx.x] += t;
            __syncthreads();
        }
        int incl = buf[threadIdx.x];
        int excl = incl - v;
        int c = carry_s;
        if (i < N) {
            off[i] = c + excl;
            cursor[i] = c + excl;
        }
        __syncthreads();
        if (threadIdx.x == 1023) carry_s = c + incl;
        __syncthreads();
    }
    if (threadIdx.x == 0) off[N] = carry_s;
}

__global__ void fill_csr(const int* __restrict__ src, const int* __restrict__ dst,
                         int* __restrict__ cursor, int* __restrict__ csr, int E)
{
    int e = blockIdx.x * blockDim.x + threadIdx.x;
    if (e < E) {
        int p = atomicAdd(&cursor[dst[e]], 1);
        csr[p] = src[e];
    }
}

// ---- conv1: h_g1 = relu(mean_nbr(y1l) + b + y1r), D=256; one wave/node ----
__global__ __launch_bounds__(256) void sage1_gather(
    const float* __restrict__ y1l, const float* __restrict__ y1r,
    const int* __restrict__ off, const int* __restrict__ csr,
    const float* __restrict__ b, float* __restrict__ out, int N)
{
    int lane = threadIdx.x & 63;
    int node = blockIdx.x * 4 + (threadIdx.x >> 6);
    if (node >= N) return;
    int s = off[node], e = off[node + 1];
    float4 acc = {0.f, 0.f, 0.f, 0.f};
    if (s < e) {
        int j = csr[s];
        for (int p = s; p + 1 < e; ++p) {
            int jn = csr[p + 1];
            const float4 v = ((const float4*)(y1l + (size_t)j * 256))[lane];
            acc.x += v.x; acc.y += v.y; acc.z += v.z; acc.w += v.w;
            j = jn;
        }
        const float4 v = ((const float4*)(y1l + (size_t)j * 256))[lane];
        acc.x += v.x; acc.y += v.y; acc.z += v.z; acc.w += v.w;
    }
    float inv = (e > s) ? 1.0f / (float)(e - s) : 1.0f;
    const float4 yr = ((const float4*)(y1r + (size_t)node * 256))[lane];
    const float4 bb = ((const float4*)b)[lane];
    float4 o;
    o.x = fmaxf(acc.x * inv + bb.x + yr.x, 0.0f);
    o.y = fmaxf(acc.y * inv + bb.y + yr.y, 0.0f);
    o.z = fmaxf(acc.z * inv + bb.z + yr.z, 0.0f);
    o.w = fmaxf(acc.w * inv + bb.w + yr.w, 0.0f);
    ((float4*)(out + (size_t)node * 256))[lane] = o;
}

// ---- conv2: h_g = l2norm(mean_nbr(y2l) + b + y2r), D=128; one wave/node ----
__global__ __launch_bounds__(256) void sage2_gather_norm(
    const float* __restrict__ y2l, const float* __restrict__ y2r,
    const int* __restrict__ off, const int* __restrict__ csr,
    const float* __restrict__ b, float* __restrict__ out, int N)
{
    int lane = threadIdx.x & 63;
    int node = blockIdx.x * 4 + (threadIdx.x >> 6);
    if (node >= N) return;
    int s = off[node], e = off[node + 1];
    float2 acc = {0.f, 0.f};
    if (s < e) {
        int j = csr[s];
        for (int p = s; p + 1 < e; ++p) {
            int jn = csr[p + 1];
            const float2 v = ((const float2*)(y2l + (size_t)j * 128))[lane];
            acc.x += v.x; acc.y += v.y;
            j = jn;
        }
        const float2 v = ((const float2*)(y2l + (size_t)j * 128))[lane];
        acc.x += v.x; acc.y += v.y;
    }
    float inv = (e > s) ? 1.0f / (float)(e - s) : 1.0f;
    const float2 yr = ((const float2*)(y2r + (size_t)node * 128))[lane];
    const float2 bb = ((const float2*)b)[lane];
    float2 h;
    h.x = acc.x * inv + bb.x + yr.x;
    h.y = acc.y * inv + bb.y + yr.y;
    float ss = h.x * h.x + h.y * h.y;
    #pragma unroll
    for (int o = 32; o; o >>= 1) ss += __shfl_xor(ss, o);
    float sc = 1.0f / fmaxf(sqrtf(ss), 1e-12f);
    ((float2*)(out + (size_t)node * 128))[lane] = make_float2(h.x * sc, h.y * sc);
}

// ---- logits = hidden[N,256] @ Wc2[256,14] + bc2 ----
__global__ __launch_bounds__(256) void logits_kernel(
    const float* __restrict__ hidden, const float* __restrict__ W,
    const float* __restrict__ b, float* __restrict__ out, int N)
{
    __shared__ float Ws[256 * 14];
    __shared__ float bs[14];
    for (int i = threadIdx.x; i < 256 * 14; i += 256) Ws[i] = W[i];
    if (threadIdx.x < 14) bs[threadIdx.x] = b[threadIdx.x];
    __syncthreads();
    int c = threadIdx.x & 15;
    int r = threadIdx.x >> 4;
    int row = blockIdx.x * 16 + r;
    if (row >= N || c >= 14) return;
    const float* h = hidden + (size_t)row * 256;
    float acc = 0.0f;
    #pragma unroll 4
    for (int k4 = 0; k4 < 64; ++k4) {
        float4 hv = ((const float4*)h)[k4];
        acc += hv.x * Ws[(k4 * 4 + 0) * 14 + c];
        acc += hv.y * Ws[(k4 * 4 + 1) * 14 + c];
        acc += hv.z * Ws[(k4 * 4 + 2) * 14 + c];
        acc += hv.w * Ws[(k4 * 4 + 3) * 14 + c];
    }
    out[(size_t)row * 14 + c] = acc + bs[c];
}

extern "C" void kernel_launch(void* const* d_in, const int* in_sizes, int n_in,
                              void* d_out, int out_size, void* d_ws, size_t ws_size,
                              hipStream_t stream)
{
    const float* h_v   = (const float*)d_in[0];
    const float* h_t   = (const float*)d_in[1];
    const float* h_tab = (const float*)d_in[2];
    const int*   eidx  = (const int*)d_in[3];
    const float* W1l = (const float*)d_in[4];
    const float* W1r = (const float*)d_in[5];
    const float* b1g = (const float*)d_in[6];
    const float* W2l = (const float*)d_in[7];
    const float* W2r = (const float*)d_in[8];
    const float* b2g = (const float*)d_in[9];
    const float* Wsh = (const float*)d_in[10];
    const float* bsh = (const float*)d_in[11];
    const float* Wst = (const float*)d_in[12];
    const float* bst = (const float*)d_in[13];
    const float* Wstab = (const float*)d_in[14];
    const float* bstab = (const float*)d_in[15];
    const float* Wc1 = (const float*)d_in[16];
    const float* bc1 = (const float*)d_in[17];
    const float* Wc2 = (const float*)d_in[18];
    const float* bc2 = (const float*)d_in[19];

    const int N = in_sizes[0] / 128;      // 50000
    const int E = in_sizes[3] / 2;        // 500000
    const int* src = eidx;
    const int* dst = eidx + E;

    // ---- workspace layout ----
    // ints first: deg[N], off[N+1], cursor[N], csr[E]
    int* ip = (int*)d_ws;
    int* deg    = ip;
    int* off    = deg + N;
    int* cursor = off + N + 1;
    int* csr    = cursor + N;
    size_t int_words = (size_t)3 * N + 1 + E;
    // floats after (256-aligned)
    float* fbase = (float*)d_ws + ((int_words + 255) & ~(size_t)255);
    float* bufA = fbase;                          // y1l -> {y2l|y2r} -> hidden
    float* bufB = bufA + (size_t)N * 256;         // y1r -> h_g
    // h_g1 staged in d_out tail (overwritten later by z_/projections)

    float* out    = (float*)d_out;
    float* logits = out;
    float* z_sh   = out + (size_t)N * 14;
    float* z_t    = z_sh + (size_t)N * 128;
    float* z_tab  = z_t + (size_t)N * 128;

    float* hg1 = out + (size_t)N * 14;            // [N,256] scratch in d_out

    const int gx = (N + 63) / 64;  // 782

    // ---- CSR build ----
    hipMemsetAsync(deg, 0, (size_t)N * 4, stream);
    count_deg<<<(E + 255) / 256, 256, 0, stream>>>(dst, deg, E);
    scan_offsets<<<1, 1024, 0, stream>>>(deg, off, cursor, N);
    fill_csr<<<(E + 255) / 256, 256, 0, stream>>>(src, dst, cursor, csr, E);

    // ---- conv1 GEMMs: [N,384] x [384,256] ----
    gemm_tile<<<dim3(gx, 4), 256, 0, stream>>>(h_v, h_t, h_tab, nullptr,
        W1l, nullptr, bufA, N, 384, 256, 1, 0);
    gemm_tile<<<dim3(gx, 4), 256, 0, stream>>>(h_v, h_t, h_tab, nullptr,
        W1r, nullptr, bufB, N, 384, 256, 1, 0);

    // ---- conv1 gather + epilogue -> h_g1 ----
    sage1_gather<<<(N + 3) / 4, 256, 0, stream>>>(bufA, bufB, off, csr, b1g, hg1, N);

    // ---- conv2 GEMMs: [N,256] x [256,128] ----
    float* y2l = bufA;
    float* y2r = bufA + (size_t)N * 128;
    gemm_tile<<<dim3(gx, 2), 256, 0, stream>>>(hg1, nullptr, nullptr, nullptr,
        W2l, nullptr, y2l, N, 256, 128, 0, 0);
    gemm_tile<<<dim3(gx, 2), 256, 0, stream>>>(hg1, nullptr, nullptr, nullptr,
        W2r, nullptr, y2r, N, 256, 128, 0, 0);

    // ---- conv2 gather + l2norm -> h_g ----
    float* hg = bufB;  // [N,128]
    sage2_gather_norm<<<(N + 3) / 4, 256, 0, stream>>>(y2l, y2r, off, csr, b2g, hg, N);

    // ---- projections -> d_out (overwrites hg1 scratch; hg1 dead) ----
    gemm_tile<<<dim3(gx, 2), 256, 0, stream>>>(hg, nullptr, nullptr, nullptr,
        Wsh, bsh, z_sh, N, 128, 128, 0, 0);
    gemm_tile<<<dim3(gx, 2), 256, 0, stream>>>(h_t, nullptr, nullptr, nullptr,
        Wst, bst, z_t, N, 128, 128, 0, 0);
    gemm_tile<<<dim3(gx, 2), 256, 0, stream>>>(h_tab, nullptr, nullptr, nullptr,
        Wstab, bstab, z_tab, N, 128, 128, 0, 0);

    // ---- classifier layer 1: [N,512] x [512,256], relu ----
    float* hidden = bufA;
    gemm_tile<<<dim3(gx, 4), 256, 0, stream>>>(z_sh, z_t, z_tab, hg,
        Wc1, bc1, hidden, N, 512, 256, 1, 1);

    // ---- classifier layer 2: [N,256] x [256,14] ----
    logits_kernel<<<(N + 15) / 16, 256, 0, stream>>>(hidden, Wc2, bc2, logits, N);
}

// Round 3
// 785.387 us; speedup vs baseline: 4.3877x; 1.4143x over previous
//
#include <hip/hip_runtime.h>
#include <math.h>

typedef __attribute__((ext_vector_type(8))) short short8;
typedef __attribute__((ext_vector_type(4))) float f32x4;

static __device__ __forceinline__ unsigned short f2bf(float f) {
    union { float f; unsigned int u; } v; v.f = f;
    unsigned int r = v.u + 0x7fffu + ((v.u >> 16) & 1u);
    return (unsigned short)(r >> 16);
}

// ---- convert concat(h_v,h_t,h_tab) fp32 -> Xbf [N,384] bf16 ----
__global__ void convert_x(const float* __restrict__ hv, const float* __restrict__ ht,
                          const float* __restrict__ htab, unsigned short* __restrict__ X,
                          int total /* N*96 float4s */)
{
    int idx = blockIdx.x * blockDim.x + threadIdx.x;
    if (idx >= total) return;
    int r = idx / 96;
    int c4 = idx - r * 96;
    int seg = c4 >> 5;
    const float* s = (seg == 0) ? hv : (seg == 1) ? ht : htab;
    float4 v = ((const float4*)s)[(size_t)r * 32 + (c4 & 31)];
    ushort4 o;
    o.x = f2bf(v.x); o.y = f2bf(v.y); o.z = f2bf(v.z); o.w = f2bf(v.w);
    *(ushort4*)(X + (size_t)r * 384 + c4 * 4) = o;
}

// ---- convert + transpose all weights to bf16 Wt[n][k] ----
struct WDesc { const float* src; int K; int N; int dstoff; };
struct WPack { WDesc w[8]; };
__global__ void convert_w(WPack p, unsigned short* __restrict__ dst)
{
    WDesc d = p.w[blockIdx.y];
    int total = d.K * d.N;
    for (int i = blockIdx.x * blockDim.x + threadIdx.x; i < total;
         i += gridDim.x * blockDim.x) {
        int k = i / d.N, n = i - k * d.N;
        dst[d.dstoff + (size_t)n * d.K + k] = f2bf(d.src[i]);
    }
}

// ---- bf16 MFMA GEMM: C[M,NN] = A[M,K](bf16,lda) @ Bt[NN,K]^T + bias ----
// BM=128 BN=64 BK=64; 4 waves 2x2; XOR-swizzled LDS; dual fp32/bf16 output.
__global__ __launch_bounds__(256) void gemm_mfma(
    const unsigned short* __restrict__ A, int lda,
    const unsigned short* __restrict__ Bt,
    const float* __restrict__ bias,
    float* __restrict__ Cf, int ldcf,
    unsigned short* __restrict__ Cb, int ldcb,
    int M, int K, int relu)
{
    __shared__ __align__(16) unsigned short As[128 * 64];
    __shared__ __align__(16) unsigned short Bs[64 * 64];
    const int tid = threadIdx.x;
    const int lane = tid & 63;
    const int wid = tid >> 6;
    const int wr = wid >> 1, wc = wid & 1;
    const int m0 = blockIdx.x * 128;
    const int n0 = blockIdx.y * 64;
    const int srow = tid >> 3;   // staging row 0..31
    const int sc8  = tid & 7;    // 16B chunk within 128B row

    f32x4 acc[4][2] = {};

    for (int k0 = 0; k0 < K; k0 += 64) {
        uint4 ar[4], br[2];
        #pragma unroll
        for (int i = 0; i < 4; ++i) {
            int row = i * 32 + srow;
            int rg = m0 + row; if (rg > M - 1) rg = M - 1;
            ar[i] = *(const uint4*)(A + (size_t)rg * lda + k0 + sc8 * 8);
        }
        #pragma unroll
        for (int i = 0; i < 2; ++i) {
            int row = i * 32 + srow;
            br[i] = *(const uint4*)(Bt + (size_t)(n0 + row) * K + k0 + sc8 * 8);
        }
        __syncthreads();   // previous compute done reading LDS
        #pragma unroll
        for (int i = 0; i < 4; ++i) {
            int row = i * 32 + srow;
            *(uint4*)(As + row * 64 + ((sc8 ^ (row & 7)) * 8)) = ar[i];
        }
        #pragma unroll
        for (int i = 0; i < 2; ++i) {
            int row = i * 32 + srow;
            *(uint4*)(Bs + row * 64 + ((sc8 ^ (row & 7)) * 8)) = br[i];
        }
        __syncthreads();
        #pragma unroll
        for (int kk = 0; kk < 2; ++kk) {
            int g = kk * 4 + (lane >> 4);
            short8 a[4], b[2];
            #pragma unroll
            for (int mi = 0; mi < 4; ++mi) {
                int row = wr * 64 + mi * 16 + (lane & 15);
                a[mi] = *(const short8*)(As + row * 64 + ((g ^ (row & 7)) * 8));
            }
            #pragma unroll
            for (int ni = 0; ni < 2; ++ni) {
                int row = wc * 32 + ni * 16 + (lane & 15);
                b[ni] = *(const short8*)(Bs + row * 64 + ((g ^ (row & 7)) * 8));
            }
            #pragma unroll
            for (int mi = 0; mi < 4; ++mi)
                #pragma unroll
                for (int ni = 0; ni < 2; ++ni)
                    acc[mi][ni] = __builtin_amdgcn_mfma_f32_16x16x32_bf16(
                        a[mi], b[ni], acc[mi][ni], 0, 0, 0);
        }
    }

    #pragma unroll
    for (int mi = 0; mi < 4; ++mi) {
        #pragma unroll
        for (int ni = 0; ni < 2; ++ni) {
            int col = n0 + wc * 32 + ni * 16 + (lane & 15);
            float bv = bias ? bias[col] : 0.0f;
            #pragma unroll
            for (int j = 0; j < 4; ++j) {
                int r = m0 + wr * 64 + mi * 16 + (lane >> 4) * 4 + j;
                if (r < M) {
                    float x = acc[mi][ni][j] + bv;
                    if (relu) x = fmaxf(x, 0.0f);
                    if (Cf) Cf[(size_t)r * ldcf + col] = x;
                    if (Cb) Cb[(size_t)r * ldcb + col] = f2bf(x);
                }
            }
        }
    }
}

// ---- CSR build ----
__global__ void count_deg(const int* __restrict__ dst, int* __restrict__ deg, int E)
{
    int e = blockIdx.x * blockDim.x + threadIdx.x;
    if (e < E) atomicAdd(&deg[dst[e]], 1);
}

__global__ __launch_bounds__(1024) void scan_offsets(
    const int* __restrict__ deg, int* __restrict__ off,
    int* __restrict__ cursor, int N)
{
    __shared__ int buf[1024];
    __shared__ int carry_s;
    if (threadIdx.x == 0) carry_s = 0;
    __syncthreads();
    for (int base = 0; base < N; base += 1024) {
        int i = base + threadIdx.x;
        int v = (i < N) ? deg[i] : 0;
        buf[threadIdx.x] = v;
        __syncthreads();
        #pragma unroll
        for (int o = 1; o < 1024; o <<= 1) {
            int t = (threadIdx.x >= o) ? buf[threadIdx.x - o] : 0;
            __syncthreads();
            buf[threadIdx.x] += t;
            __syncthreads();
        }
        int incl = buf[threadIdx.x];
        int excl = incl - v;
        int c = carry_s;
        if (i < N) {
            off[i] = c + excl;
            cursor[i] = c + excl;
        }
        __syncthreads();
        if (threadIdx.x == 1023) carry_s = c + incl;
        __syncthreads();
    }
    if (threadIdx.x == 0) off[N] = carry_s;
}

__global__ void fill_csr(const int* __restrict__ src, const int* __restrict__ dst,
                         int* __restrict__ cursor, int* __restrict__ csr, int E)
{
    int e = blockIdx.x * blockDim.x + threadIdx.x;
    if (e < E) {
        int p = atomicAdd(&cursor[dst[e]], 1);
        csr[p] = src[e];
    }
}

// ---- conv1 epilogue: h_g1 = relu(mean_nbr(y1l)+b+y1r) -> bf16 [N,256] ----
__global__ __launch_bounds__(256) void sage1_gather(
    const float* __restrict__ y1l, const float* __restrict__ y1r,
    const int* __restrict__ off, const int* __restrict__ csr,
    const float* __restrict__ b, unsigned short* __restrict__ out, int N)
{
    int lane = threadIdx.x & 63;
    int node = blockIdx.x * 4 + (threadIdx.x >> 6);
    if (node >= N) return;
    int s = off[node], e = off[node + 1];
    float4 acc = {0.f, 0.f, 0.f, 0.f};
    for (int p = s; p < e; ++p) {
        int j = csr[p];
        const float4 v = ((const float4*)(y1l + (size_t)j * 256))[lane];
        acc.x += v.x; acc.y += v.y; acc.z += v.z; acc.w += v.w;
    }
    float inv = (e > s) ? 1.0f / (float)(e - s) : 1.0f;
    const float4 yr = ((const float4*)(y1r + (size_t)node * 256))[lane];
    const float4 bb = ((const float4*)b)[lane];
    ushort4 o;
    o.x = f2bf(fmaxf(acc.x * inv + bb.x + yr.x, 0.0f));
    o.y = f2bf(fmaxf(acc.y * inv + bb.y + yr.y, 0.0f));
    o.z = f2bf(fmaxf(acc.z * inv + bb.z + yr.z, 0.0f));
    o.w = f2bf(fmaxf(acc.w * inv + bb.w + yr.w, 0.0f));
    *(ushort4*)(out + (size_t)node * 256 + lane * 4) = o;
}

// ---- conv2 epilogue: h_g = l2norm(mean+b+root) -> bf16 into cls_bf seg3 ----
__global__ __launch_bounds__(256) void sage2_gather_norm(
    const float* __restrict__ y2l, const float* __restrict__ y2r,
    const int* __restrict__ off, const int* __restrict__ csr,
    const float* __restrict__ b, unsigned short* __restrict__ outb, int N)
{
    int lane = threadIdx.x & 63;
    int node = blockIdx.x * 4 + (threadIdx.x >> 6);
    if (node >= N) return;
    int s = off[node], e = off[node + 1];
    float2 acc = {0.f, 0.f};
    for (int p = s; p < e; ++p) {
        int j = csr[p];
        const float2 v = ((const float2*)(y2l + (size_t)j * 128))[lane];
        acc.x += v.x; acc.y += v.y;
    }
    float inv = (e > s) ? 1.0f / (float)(e - s) : 1.0f;
    const float2 yr = ((const float2*)(y2r + (size_t)node * 128))[lane];
    const float2 bb = ((const float2*)b)[lane];
    float2 h;
    h.x = acc.x * inv + bb.x + yr.x;
    h.y = acc.y * inv + bb.y + yr.y;
    float ss = h.x * h.x + h.y * h.y;
    #pragma unroll
    for (int o = 32; o; o >>= 1) ss += __shfl_xor(ss, o);
    float sc = 1.0f / fmaxf(sqrtf(ss), 1e-12f);
    ushort2 o2; o2.x = f2bf(h.x * sc); o2.y = f2bf(h.y * sc);
    *(ushort2*)(outb + (size_t)node * 512 + lane * 2) = o2;
}

// ---- logits = hidden[N,256] @ Wc2[256,14] + bc2 ----
__global__ __launch_bounds__(256) void logits_kernel(
    const float* __restrict__ hidden, const float* __restrict__ W,
    const float* __restrict__ b, float* __restrict__ out, int N)
{
    __shared__ float Ws[256 * 14];
    __shared__ float bs[14];
    for (int i = threadIdx.x; i < 256 * 14; i += 256) Ws[i] = W[i];
    if (threadIdx.x < 14) bs[threadIdx.x] = b[threadIdx.x];
    __syncthreads();
    int c = threadIdx.x & 15;
    int r = threadIdx.x >> 4;
    int row = blockIdx.x * 16 + r;
    if (row >= N || c >= 14) return;
    const float* h = hidden + (size_t)row * 256;
    float acc = 0.0f;
    #pragma unroll 4
    for (int k4 = 0; k4 < 64; ++k4) {
        float4 hv = ((const float4*)h)[k4];
        acc += hv.x * Ws[(k4 * 4 + 0) * 14 + c];
        acc += hv.y * Ws[(k4 * 4 + 1) * 14 + c];
        acc += hv.z * Ws[(k4 * 4 + 2) * 14 + c];
        acc += hv.w * Ws[(k4 * 4 + 3) * 14 + c];
    }
    out[(size_t)row * 14 + c] = acc + bs[c];
}

extern "C" void kernel_launch(void* const* d_in, const int* in_sizes, int n_in,
                              void* d_out, int out_size, void* d_ws, size_t ws_size,
                              hipStream_t stream)
{
    const float* h_v   = (const float*)d_in[0];
    const float* h_t   = (const float*)d_in[1];
    const float* h_tab = (const float*)d_in[2];
    const int*   eidx  = (const int*)d_in[3];
    const float* W1l = (const float*)d_in[4];
    const float* W1r = (const float*)d_in[5];
    const float* b1g = (const float*)d_in[6];
    const float* W2l = (const float*)d_in[7];
    const float* W2r = (const float*)d_in[8];
    const float* b2g = (const float*)d_in[9];
    const float* Wsh = (const float*)d_in[10];
    const float* bsh = (const float*)d_in[11];
    const float* Wst = (const float*)d_in[12];
    const float* bst = (const float*)d_in[13];
    const float* Wstab = (const float*)d_in[14];
    const float* bstab = (const float*)d_in[15];
    const float* Wc1 = (const float*)d_in[16];
    const float* bc1 = (const float*)d_in[17];
    const float* Wc2 = (const float*)d_in[18];
    const float* bc2 = (const float*)d_in[19];

    const int N = in_sizes[0] / 128;      // 50000
    const int E = in_sizes[3] / 2;        // 500000
    const int* src = eidx;
    const int* dst = eidx + E;

    // ---- workspace layout ----
    int* deg    = (int*)d_ws;
    int* off    = deg + N;
    int* cursor = off + N + 1;
    int* csr    = cursor + N;
    size_t int_bytes = ((size_t)3 * N + 1 + E) * 4;
    unsigned short* Wt  = (unsigned short*)((char*)d_ws + ((int_bytes + 255) & ~(size_t)255));
    // transposed bf16 weights, offsets:
    const int oW1l = 0, oW1r = 98304, oW2l = 196608, oW2r = 229376;
    const int oWsh = 262144, oWst = 278528, oWstab = 294912, oWc1 = 311296;
    unsigned short* Xbf = Wt + 442368;                 // [N,384] bf16
    float* R1 = (float*)(Xbf + (size_t)N * 384);       // y1l -> {y2l|y2r} -> hidden
    float* R2 = R1 + (size_t)N * 256;                  // y1r -> cls_bf
    unsigned short* cls_bf = (unsigned short*)R2;      // [N,512] bf16 (after y1r dead)

    float* out    = (float*)d_out;
    float* logits = out;
    float* z_sh   = out + (size_t)N * 14;
    float* z_t    = z_sh + (size_t)N * 128;
    float* z_tab  = z_t + (size_t)N * 128;
    // conv1 output (bf16 [N,256]) staged in d_out's z_t/z_tab region (dead until projections)
    unsigned short* hg1 = (unsigned short*)(out + (size_t)N * 14 + (size_t)N * 128);

    const int gx = (N + 127) / 128;  // 391

    // ---- CSR build ----
    hipMemsetAsync(deg, 0, (size_t)N * 4, stream);
    count_deg<<<(E + 255) / 256, 256, 0, stream>>>(dst, deg, E);
    scan_offsets<<<1, 1024, 0, stream>>>(deg, off, cursor, N);
    fill_csr<<<(E + 255) / 256, 256, 0, stream>>>(src, dst, cursor, csr, E);

    // ---- conversions ----
    convert_x<<<(N * 96 + 255) / 256, 256, 0, stream>>>(h_v, h_t, h_tab, Xbf, N * 96);
    WPack p;
    p.w[0] = {W1l, 384, 256, oW1l};   p.w[1] = {W1r, 384, 256, oW1r};
    p.w[2] = {W2l, 256, 128, oW2l};   p.w[3] = {W2r, 256, 128, oW2r};
    p.w[4] = {Wsh, 128, 128, oWsh};   p.w[5] = {Wst, 128, 128, oWst};
    p.w[6] = {Wstab, 128, 128, oWstab}; p.w[7] = {Wc1, 512, 256, oWc1};
    convert_w<<<dim3(128, 8), 256, 0, stream>>>(p, Wt);

    // ---- conv1 GEMMs: [N,384]x[384,256] ----
    float* y1l = R1;
    float* y1r = R2;
    gemm_mfma<<<dim3(gx, 4), 256, 0, stream>>>(Xbf, 384, Wt + oW1l, nullptr,
        y1l, 256, nullptr, 0, N, 384, 0);
    gemm_mfma<<<dim3(gx, 4), 256, 0, stream>>>(Xbf, 384, Wt + oW1r, nullptr,
        y1r, 256, nullptr, 0, N, 384, 0);

    // ---- conv1 gather -> h_g1 (bf16) ----
    sage1_gather<<<(N + 3) / 4, 256, 0, stream>>>(y1l, y1r, off, csr, b1g, hg1, N);

    // ---- conv2 GEMMs: [N,256]x[256,128] ----
    float* y2l = R1;
    float* y2r = R1 + (size_t)N * 128;
    gemm_mfma<<<dim3(gx, 2), 256, 0, stream>>>(hg1, 256, Wt + oW2l, nullptr,
        y2l, 128, nullptr, 0, N, 256, 0);
    gemm_mfma<<<dim3(gx, 2), 256, 0, stream>>>(hg1, 256, Wt + oW2r, nullptr,
        y2r, 128, nullptr, 0, N, 256, 0);

    // ---- conv2 gather + l2norm -> h_g (bf16, cls_bf segment 3) ----
    sage2_gather_norm<<<(N + 3) / 4, 256, 0, stream>>>(y2l, y2r, off, csr, b2g,
        cls_bf + 384, N);

    // ---- projections (fp32 out + bf16 copy into cls_bf) ----
    gemm_mfma<<<dim3(gx, 2), 256, 0, stream>>>(cls_bf + 384, 512, Wt + oWsh, bsh,
        z_sh, 128, cls_bf + 0, 512, N, 128, 0);
    gemm_mfma<<<dim3(gx, 2), 256, 0, stream>>>(Xbf + 128, 384, Wt + oWst, bst,
        z_t, 128, cls_bf + 128, 512, N, 128, 0);
    gemm_mfma<<<dim3(gx, 2), 256, 0, stream>>>(Xbf + 256, 384, Wt + oWstab, bstab,
        z_tab, 128, cls_bf + 256, 512, N, 128, 0);

    // ---- classifier layer 1: [N,512]x[512,256], relu ----
    float* hidden = R1;
    gemm_mfma<<<dim3(gx, 4), 256, 0, stream>>>(cls_bf, 512, Wt + oWc1, bc1,
        hidden, 256, nullptr, 0, N, 512, 1);

    // ---- classifier layer 2 ----
    logits_kernel<<<(N + 15) / 16, 256, 0, stream>>>(hidden, Wc2, bc2, logits, N);
}

// Round 4
// 564.852 us; speedup vs baseline: 6.1008x; 1.3904x over previous
//
#include <hip/hip_runtime.h>
#include <math.h>

typedef __attribute__((ext_vector_type(8))) short short8;
typedef __attribute__((ext_vector_type(4))) float f32x4;

static __device__ __forceinline__ unsigned short f2bf(float f) {
    union { float f; unsigned int u; } v; v.f = f;
    unsigned int r = v.u + 0x7fffu + ((v.u >> 16) & 1u);
    return (unsigned short)(r >> 16);
}
static __device__ __forceinline__ float bflo(unsigned int u) {
    union { unsigned int u; float f; } v; v.u = u << 16; return v.f;
}
static __device__ __forceinline__ float bfhi(unsigned int u) {
    union { unsigned int u; float f; } v; v.u = u & 0xffff0000u; return v.f;
}

// ---- convert concat(h_v,h_t,h_tab) fp32 -> Xbf [N,384] bf16 ----
__global__ void convert_x(const float* __restrict__ hv, const float* __restrict__ ht,
                          const float* __restrict__ htab, unsigned short* __restrict__ X,
                          int total /* N*96 float4s */)
{
    int idx = blockIdx.x * blockDim.x + threadIdx.x;
    if (idx >= total) return;
    int r = idx / 96;
    int c4 = idx - r * 96;
    int seg = c4 >> 5;
    const float* s = (seg == 0) ? hv : (seg == 1) ? ht : htab;
    float4 v = ((const float4*)s)[(size_t)r * 32 + (c4 & 31)];
    ushort4 o;
    o.x = f2bf(v.x); o.y = f2bf(v.y); o.z = f2bf(v.z); o.w = f2bf(v.w);
    *(ushort4*)(X + (size_t)r * 384 + c4 * 4) = o;
}

// ---- convert + transpose all weights to bf16 Wt[n][k] ----
struct WDesc { const float* src; int K; int N; int dstoff; };
struct WPack { WDesc w[9]; };
__global__ void convert_w(WPack p, unsigned short* __restrict__ dst)
{
    WDesc d = p.w[blockIdx.y];
    int total = d.K * d.N;
    for (int i = blockIdx.x * blockDim.x + threadIdx.x; i < total;
         i += gridDim.x * blockDim.x) {
        int k = i / d.N, n = i - k * d.N;
        dst[d.dstoff + (size_t)n * d.K + k] = f2bf(d.src[i]);
    }
}

// ---------------------------------------------------------------------------
// bf16 MFMA GEMM: out[M, gridDim.y*BN] = A[M,K](bf16,lda) @ Bt[cols][K]^T
// BM=128, BK=64, 8 waves (2x4), XOR-swizzled LDS.
// MODE 0: bf16 output only (Cb)
// MODE 1: bias + dual fp32 (Cf) + bf16 (Cb)
// MODE 2: bias + relu -> hidden in LDS -> fused logits = hid @ Wc2t + bc2
// ---------------------------------------------------------------------------
template<int BN, int MODE>
__global__ __launch_bounds__(512) void gemm2(
    const unsigned short* __restrict__ A, int lda,
    const unsigned short* __restrict__ Bt,
    const float* __restrict__ bias,
    float* __restrict__ Cf, int ldcf,
    unsigned short* __restrict__ Cb, int ldcb,
    const unsigned short* __restrict__ Wc2t,
    const float* __restrict__ bc2,
    float* __restrict__ logits,
    int M, int K)
{
    constexpr int NI = BN / 64;
    constexpr int SMEM_SHORTS = (MODE == 2) ? (128 * 256) : (128 * 64 + BN * 64);
    __shared__ __align__(16) unsigned short smem[SMEM_SHORTS];
    unsigned short* As = smem;
    unsigned short* Bs = smem + 128 * 64;
    const int tid = threadIdx.x;
    const int lane = tid & 63;
    const int wid = tid >> 6;          // 0..7
    const int wr = wid >> 2;           // 0..1 (64-row slab)
    const int wc = wid & 3;            // 0..3 (BN/4-col slab)
    const int m0 = blockIdx.x * 128;
    const int n0 = blockIdx.y * BN;
    const int srow = tid >> 3;         // 0..63
    const int sc8 = tid & 7;           // 16B chunk in 128B row

    f32x4 acc[4][NI] = {};

    for (int k0 = 0; k0 < K; k0 += 64) {
        uint4 ar[2], br[NI];
        #pragma unroll
        for (int i = 0; i < 2; ++i) {
            int row = i * 64 + srow;
            int rg = m0 + row; if (rg > M - 1) rg = M - 1;
            ar[i] = *(const uint4*)(A + (size_t)rg * lda + k0 + sc8 * 8);
        }
        #pragma unroll
        for (int i = 0; i < NI; ++i) {
            int row = i * 64 + srow;
            br[i] = *(const uint4*)(Bt + (size_t)(n0 + row) * K + k0 + sc8 * 8);
        }
        __syncthreads();
        #pragma unroll
        for (int i = 0; i < 2; ++i) {
            int row = i * 64 + srow;
            *(uint4*)(As + row * 64 + ((sc8 ^ (row & 7)) * 8)) = ar[i];
        }
        #pragma unroll
        for (int i = 0; i < NI; ++i) {
            int row = i * 64 + srow;
            *(uint4*)(Bs + row * 64 + ((sc8 ^ (row & 7)) * 8)) = br[i];
        }
        __syncthreads();
        #pragma unroll
        for (int kk = 0; kk < 2; ++kk) {
            int g = kk * 4 + (lane >> 4);
            short8 a[4], b[NI];
            #pragma unroll
            for (int mi = 0; mi < 4; ++mi) {
                int row = wr * 64 + mi * 16 + (lane & 15);
                a[mi] = *(const short8*)(As + row * 64 + ((g ^ (row & 7)) * 8));
            }
            #pragma unroll
            for (int ni = 0; ni < NI; ++ni) {
                int row = wc * (BN / 4) + ni * 16 + (lane & 15);
                b[ni] = *(const short8*)(Bs + row * 64 + ((g ^ (row & 7)) * 8));
            }
            #pragma unroll
            for (int mi = 0; mi < 4; ++mi)
                #pragma unroll
                for (int ni = 0; ni < NI; ++ni)
                    acc[mi][ni] = __builtin_amdgcn_mfma_f32_16x16x32_bf16(
                        a[mi], b[ni], acc[mi][ni], 0, 0, 0);
        }
    }

    if (MODE == 2) __syncthreads();  // As/Bs reads done before hid overwrite

    #pragma unroll
    for (int mi = 0; mi < 4; ++mi) {
        #pragma unroll
        for (int ni = 0; ni < NI; ++ni) {
            int colL = wc * (BN / 4) + ni * 16 + (lane & 15);
            int col = n0 + colL;
            float bv = bias ? bias[col] : 0.0f;
            #pragma unroll
            for (int j = 0; j < 4; ++j) {
                int rL = wr * 64 + mi * 16 + (lane >> 4) * 4 + j;
                int r = m0 + rL;
                float x = acc[mi][ni][j] + bv;
                if (MODE == 2) {
                    x = fmaxf(x, 0.0f);
                    int c8 = colL >> 3;
                    smem[rL * 256 + ((c8 ^ (rL & 7)) * 8) + (colL & 7)] = f2bf(x);
                } else if (r < M) {
                    if (MODE == 1) {
                        Cf[(size_t)r * ldcf + col] = x;
                        Cb[(size_t)r * ldcb + col] = f2bf(x);
                    } else {
                        Cb[(size_t)r * ldcb + col] = f2bf(x);
                    }
                }
            }
        }
    }

    if (MODE == 2) {
        __syncthreads();
        // logits: wave wid handles rows wid*16..wid*16+15; K=256, 8 MFMA
        f32x4 lacc = {0.f, 0.f, 0.f, 0.f};
        int rL = wid * 16 + (lane & 15);
        #pragma unroll
        for (int k0 = 0; k0 < 256; k0 += 32) {
            int c8 = (k0 >> 3) + (lane >> 4);
            short8 a = *(const short8*)(smem + rL * 256 + ((c8 ^ (rL & 7)) * 8));
            short8 b = *(const short8*)(Wc2t + (lane & 15) * 256 + k0 + (lane >> 4) * 8);
            lacc = __builtin_amdgcn_mfma_f32_16x16x32_bf16(a, b, lacc, 0, 0, 0);
        }
        int colL = lane & 15;
        if (colL < 14) {
            float bb = bc2[colL];
            #pragma unroll
            for (int j = 0; j < 4; ++j) {
                int r = m0 + wid * 16 + (lane >> 4) * 4 + j;
                if (r < M) logits[(size_t)r * 14 + colL] = lacc[j] + bb;
            }
        }
    }
}

// ---- CSR build ----
__global__ void count_deg(const int* __restrict__ dst, int* __restrict__ deg, int E)
{
    int e = blockIdx.x * blockDim.x + threadIdx.x;
    if (e < E) atomicAdd(&deg[dst[e]], 1);
}

__global__ __launch_bounds__(1024) void scan_offsets(
    const int* __restrict__ deg, int* __restrict__ off,
    int* __restrict__ cursor, int N)
{
    __shared__ int buf[1024];
    __shared__ int carry_s;
    if (threadIdx.x == 0) carry_s = 0;
    __syncthreads();
    for (int base = 0; base < N; base += 1024) {
        int i = base + threadIdx.x;
        int v = (i < N) ? deg[i] : 0;
        buf[threadIdx.x] = v;
        __syncthreads();
        #pragma unroll
        for (int o = 1; o < 1024; o <<= 1) {
            int t = (threadIdx.x >= o) ? buf[threadIdx.x - o] : 0;
            __syncthreads();
            buf[threadIdx.x] += t;
            __syncthreads();
        }
        int incl = buf[threadIdx.x];
        int excl = incl - v;
        int c = carry_s;
        if (i < N) {
            off[i] = c + excl;
            cursor[i] = c + excl;
        }
        __syncthreads();
        if (threadIdx.x == 1023) carry_s = c + incl;
        __syncthreads();
    }
    if (threadIdx.x == 0) off[N] = carry_s;
}

__global__ void fill_csr(const int* __restrict__ src, const int* __restrict__ dst,
                         int* __restrict__ cursor, int* __restrict__ csr, int E)
{
    int e = blockIdx.x * blockDim.x + threadIdx.x;
    if (e < E) {
        int p = atomicAdd(&cursor[dst[e]], 1);
        csr[p] = src[e];
    }
}

// ---- conv1 epilogue: h_g1 = relu(mean_nbr(y1.l)+b+y1.r) -> bf16 [N,256] ----
// y1 [N,512] bf16 layout: cols 0..255 = l-part, 256..511 = r-part
__global__ __launch_bounds__(256) void sage1_gather(
    const unsigned short* __restrict__ y1,
    const int* __restrict__ off, const int* __restrict__ csr,
    const float* __restrict__ b, unsigned short* __restrict__ out, int N)
{
    int lane = threadIdx.x & 63;
    int node = blockIdx.x * 4 + (threadIdx.x >> 6);
    if (node >= N) return;
    int s = off[node], e = off[node + 1];
    float a0 = 0.f, a1 = 0.f, a2 = 0.f, a3 = 0.f;
    for (int p = s; p < e; ++p) {
        int j = csr[p];
        uint2 v = *(const uint2*)(y1 + (size_t)j * 512 + lane * 4);
        a0 += bflo(v.x); a1 += bfhi(v.x); a2 += bflo(v.y); a3 += bfhi(v.y);
    }
    float inv = (e > s) ? 1.0f / (float)(e - s) : 1.0f;
    uint2 rv = *(const uint2*)(y1 + (size_t)node * 512 + 256 + lane * 4);
    float4 bb = ((const float4*)b)[lane];
    ushort4 o;
    o.x = f2bf(fmaxf(a0 * inv + bb.x + bflo(rv.x), 0.0f));
    o.y = f2bf(fmaxf(a1 * inv + bb.y + bfhi(rv.x), 0.0f));
    o.z = f2bf(fmaxf(a2 * inv + bb.z + bflo(rv.y), 0.0f));
    o.w = f2bf(fmaxf(a3 * inv + bb.w + bfhi(rv.y), 0.0f));
    *(ushort4*)(out + (size_t)node * 256 + lane * 4) = o;
}

// ---- conv2 epilogue: h_g = l2norm(mean+b+root) -> bf16 into cls_bf col 384 ----
// y2 [N,256] bf16: cols 0..127 = l, 128..255 = r
__global__ __launch_bounds__(256) void sage2_gather_norm(
    const unsigned short* __restrict__ y2,
    const int* __restrict__ off, const int* __restrict__ csr,
    const float* __restrict__ b, unsigned short* __restrict__ outb, int N)
{
    int lane = threadIdx.x & 63;
    int node = blockIdx.x * 4 + (threadIdx.x >> 6);
    if (node >= N) return;
    int s = off[node], e = off[node + 1];
    float a0 = 0.f, a1 = 0.f;
    for (int p = s; p < e; ++p) {
        int j = csr[p];
        unsigned int v = *(const unsigned int*)(y2 + (size_t)j * 256 + lane * 2);
        a0 += bflo(v); a1 += bfhi(v);
    }
    float inv = (e > s) ? 1.0f / (float)(e - s) : 1.0f;
    unsigned int rv = *(const unsigned int*)(y2 + (size_t)node * 256 + 128 + lane * 2);
    float2 bb = ((const float2*)b)[lane];
    float hx = a0 * inv + bb.x + bflo(rv);
    float hy = a1 * inv + bb.y + bfhi(rv);
    float ss = hx * hx + hy * hy;
    #pragma unroll
    for (int o = 32; o; o >>= 1) ss += __shfl_xor(ss, o);
    float sc = 1.0f / fmaxf(sqrtf(ss), 1e-12f);
    ushort2 o2; o2.x = f2bf(hx * sc); o2.y = f2bf(hy * sc);
    *(ushort2*)(outb + (size_t)node * 512 + lane * 2) = o2;
}

extern "C" void kernel_launch(void* const* d_in, const int* in_sizes, int n_in,
                              void* d_out, int out_size, void* d_ws, size_t ws_size,
                              hipStream_t stream)
{
    const float* h_v   = (const float*)d_in[0];
    const float* h_t   = (const float*)d_in[1];
    const float* h_tab = (const float*)d_in[2];
    const int*   eidx  = (const int*)d_in[3];
    const float* W1l = (const float*)d_in[4];
    const float* W1r = (const float*)d_in[5];
    const float* b1g = (const float*)d_in[6];
    const float* W2l = (const float*)d_in[7];
    const float* W2r = (const float*)d_in[8];
    const float* b2g = (const float*)d_in[9];
    const float* Wsh = (const float*)d_in[10];
    const float* bsh = (const float*)d_in[11];
    const float* Wst = (const float*)d_in[12];
    const float* bst = (const float*)d_in[13];
    const float* Wstab = (const float*)d_in[14];
    const float* bstab = (const float*)d_in[15];
    const float* Wc1 = (const float*)d_in[16];
    const float* bc1 = (const float*)d_in[17];
    const float* Wc2 = (const float*)d_in[18];
    const float* bc2 = (const float*)d_in[19];

    const int N = in_sizes[0] / 128;      // 50000
    const int E = in_sizes[3] / 2;        // 500000
    const int* src = eidx;
    const int* dst = eidx + E;

    // ---- workspace layout ----
    int* deg    = (int*)d_ws;
    int* off    = deg + N;
    int* cursor = off + N + 1;
    int* csr    = cursor + N;
    size_t int_bytes = ((size_t)3 * N + 1 + E) * 4;
    unsigned short* Wt = (unsigned short*)((char*)d_ws + ((int_bytes + 255) & ~(size_t)255));
    // transposed bf16 weights (contiguous l|r pairs for fused GEMMs):
    const int oW1l = 0;                    // 256*384
    const int oW1r = oW1l + 98304;         // 256*384
    const int oW2l = oW1r + 98304;         // 128*256
    const int oW2r = oW2l + 32768;         // 128*256
    const int oWsh = oW2r + 32768;         // 128*128
    const int oWst = oWsh + 16384;
    const int oWstab = oWst + 16384;
    const int oWc1 = oWstab + 16384;       // 256*512
    const int oWc2t = oWc1 + 131072;       // 16*256 (rows 14,15 zero-padded)
    const int wtotal = oWc2t + 4096;       // 446464 shorts

    unsigned short* Xbf  = Wt + wtotal;                  // [N,384] bf16
    unsigned short* bufY = Xbf + (size_t)N * 384;        // y1 [N,512] -> cls_bf [N,512]
    unsigned short* bufH = bufY + (size_t)N * 512;       // hg1 [N,256]
    unsigned short* bufY2 = bufH + (size_t)N * 256;      // y2 [N,256]

    float* out    = (float*)d_out;
    float* logits = out;
    float* z_sh   = out + (size_t)N * 14;
    float* z_t    = z_sh + (size_t)N * 128;
    float* z_tab  = z_t + (size_t)N * 128;

    const int gx = (N + 127) / 128;  // 391

    // ---- CSR build ----
    hipMemsetAsync(deg, 0, (size_t)N * 4, stream);
    hipMemsetAsync(Wt + oWc2t, 0, 16 * 256 * 2, stream);
    count_deg<<<(E + 255) / 256, 256, 0, stream>>>(dst, deg, E);
    scan_offsets<<<1, 1024, 0, stream>>>(deg, off, cursor, N);
    fill_csr<<<(E + 255) / 256, 256, 0, stream>>>(src, dst, cursor, csr, E);

    // ---- conversions ----
    convert_x<<<(N * 96 + 255) / 256, 256, 0, stream>>>(h_v, h_t, h_tab, Xbf, N * 96);
    WPack p;
    p.w[0] = {W1l, 384, 256, oW1l};     p.w[1] = {W1r, 384, 256, oW1r};
    p.w[2] = {W2l, 256, 128, oW2l};     p.w[3] = {W2r, 256, 128, oW2r};
    p.w[4] = {Wsh, 128, 128, oWsh};     p.w[5] = {Wst, 128, 128, oWst};
    p.w[6] = {Wstab, 128, 128, oWstab}; p.w[7] = {Wc1, 512, 256, oWc1};
    p.w[8] = {Wc2, 256, 14, oWc2t};
    convert_w<<<dim3(128, 9), 256, 0, stream>>>(p, Wt);

    // ---- conv1 fused GEMM: [N,384] x [384, 512(l|r)] -> y1 bf16 ----
    unsigned short* y1 = bufY;
    gemm2<256, 0><<<dim3(gx, 2), 512, 0, stream>>>(Xbf, 384, Wt + oW1l, nullptr,
        nullptr, 0, y1, 512, nullptr, nullptr, nullptr, N, 384);

    // ---- conv1 gather -> h_g1 bf16 [N,256] ----
    sage1_gather<<<(N + 3) / 4, 256, 0, stream>>>(y1, off, csr, b1g, bufH, N);

    // ---- conv2 fused GEMM: [N,256] x [256, 256(l|r)] -> y2 bf16 ----
    gemm2<256, 0><<<dim3(gx, 1), 512, 0, stream>>>(bufH, 256, Wt + oW2l, nullptr,
        nullptr, 0, bufY2, 256, nullptr, nullptr, nullptr, N, 256);

    // ---- conv2 gather + l2norm -> h_g bf16 (cls_bf col 384) ----
    unsigned short* cls_bf = bufY;  // y1 dead; reuse as [N,512] classifier input
    sage2_gather_norm<<<(N + 3) / 4, 256, 0, stream>>>(bufY2, off, csr, b2g,
        cls_bf + 384, N);

    // ---- projections: fp32 to d_out + bf16 slice into cls_bf ----
    gemm2<128, 1><<<dim3(gx, 1), 512, 0, stream>>>(cls_bf + 384, 512, Wt + oWsh, bsh,
        z_sh, 128, cls_bf + 0, 512, nullptr, nullptr, nullptr, N, 128);
    gemm2<128, 1><<<dim3(gx, 1), 512, 0, stream>>>(Xbf + 128, 384, Wt + oWst, bst,
        z_t, 128, cls_bf + 128, 512, nullptr, nullptr, nullptr, N, 128);
    gemm2<128, 1><<<dim3(gx, 1), 512, 0, stream>>>(Xbf + 256, 384, Wt + oWstab, bstab,
        z_tab, 128, cls_bf + 256, 512, nullptr, nullptr, nullptr, N, 128);

    // ---- classifier: [N,512] x [512,256] + relu, fused logits -> d_out ----
    gemm2<256, 2><<<dim3(gx, 1), 512, 0, stream>>>(cls_bf, 512, Wt + oWc1, bc1,
        nullptr, 0, nullptr, 0, Wt + oWc2t, bc2, logits, N, 512);
}

// Round 5
// 449.536 us; speedup vs baseline: 7.6658x; 1.2565x over previous
//
#include <hip/hip_runtime.h>
#include <math.h>

typedef __attribute__((ext_vector_type(8))) short short8;
typedef __attribute__((ext_vector_type(4))) float f32x4;

static __device__ __forceinline__ unsigned short f2bf(float f) {
    union { float f; unsigned int u; } v; v.f = f;
    unsigned int r = v.u + 0x7fffu + ((v.u >> 16) & 1u);
    return (unsigned short)(r >> 16);
}
static __device__ __forceinline__ float bflo(unsigned int u) {
    union { unsigned int u; float f; } v; v.u = u << 16; return v.f;
}
static __device__ __forceinline__ float bfhi(unsigned int u) {
    union { unsigned int u; float f; } v; v.u = u & 0xffff0000u; return v.f;
}

// ---- convert concat(h_v,h_t,h_tab) fp32 -> Xbf [N,384] bf16 ----
__global__ void convert_x(const float* __restrict__ hv, const float* __restrict__ ht,
                          const float* __restrict__ htab, unsigned short* __restrict__ X,
                          int total /* N*96 float4s */)
{
    int idx = blockIdx.x * blockDim.x + threadIdx.x;
    if (idx >= total) return;
    int r = idx / 96;
    int c4 = idx - r * 96;
    int seg = c4 >> 5;
    const float* s = (seg == 0) ? hv : (seg == 1) ? ht : htab;
    float4 v = ((const float4*)s)[(size_t)r * 32 + (c4 & 31)];
    ushort4 o;
    o.x = f2bf(v.x); o.y = f2bf(v.y); o.z = f2bf(v.z); o.w = f2bf(v.w);
    *(ushort4*)(X + (size_t)r * 384 + c4 * 4) = o;
}

// ---- convert + transpose all weights to bf16 Wt[n][k] ----
struct WDesc { const float* src; int K; int N; int dstoff; };
struct WPack { WDesc w[9]; };
__global__ void convert_w(WPack p, unsigned short* __restrict__ dst)
{
    WDesc d = p.w[blockIdx.y];
    int total = d.K * d.N;
    for (int i = blockIdx.x * blockDim.x + threadIdx.x; i < total;
         i += gridDim.x * blockDim.x) {
        int k = i / d.N, n = i - k * d.N;
        dst[d.dstoff + (size_t)n * d.K + k] = f2bf(d.src[i]);
    }
}

// ---------------------------------------------------------------------------
// bf16 MFMA GEMM with 2-phase prefetch and LDS-staged coalesced writeback.
// BM=128, BK=64, 8 waves (2x4).
// MODE 0: bf16 out only. MODE 1: bias + fp32 out + bf16 out (blockIdx.z
// selects one of 3 param sets). MODE 2: bias+relu -> LDS hidden -> fused
// logits GEMM.
// ---------------------------------------------------------------------------
struct GemmP {
    const unsigned short* A; int lda;
    const unsigned short* Bt;
    const float* bias;
    float* Cf; int ldcf;
    unsigned short* Cb; int ldcb;
};
struct GemmP3 { GemmP q[3]; };

template<int BN, int MODE>
__global__ __launch_bounds__(512) void gemm3(
    GemmP3 ps,
    const unsigned short* __restrict__ Wc2t,
    const float* __restrict__ bc2,
    float* __restrict__ logits,
    int M, int K)
{
    constexpr int NI = BN / 64;
    constexpr int SMEM_SHORTS = (MODE == 2) ? (128 * 256) : (128 * 64 + BN * 64);
    __shared__ __align__(16) unsigned short smem[SMEM_SHORTS];
    unsigned short* As = smem;
    unsigned short* Bs = smem + 128 * 64;
    const GemmP P = ps.q[(MODE == 1) ? blockIdx.z : 0];
    const int tid = threadIdx.x;
    const int lane = tid & 63;
    const int wid = tid >> 6;          // 0..7
    const int wr = wid >> 2;           // 0..1
    const int wc = wid & 3;            // 0..3
    const int m0 = blockIdx.x * 128;
    const int n0 = blockIdx.y * BN;
    const int srow = tid >> 3;         // 0..63
    const int sc8 = tid & 7;

    f32x4 acc[4][NI] = {};
    uint4 ar[2], br[NI];

    const int nt = K >> 6;
    // prologue: load tile 0
    #pragma unroll
    for (int i = 0; i < 2; ++i) {
        int rg = m0 + i * 64 + srow; if (rg > M - 1) rg = M - 1;
        ar[i] = *(const uint4*)(P.A + (size_t)rg * P.lda + sc8 * 8);
    }
    #pragma unroll
    for (int i = 0; i < NI; ++i)
        br[i] = *(const uint4*)(P.Bt + (size_t)(n0 + i * 64 + srow) * K + sc8 * 8);

    for (int t = 0; t < nt; ++t) {
        __syncthreads();               // LDS consumers of prev tile done
        #pragma unroll
        for (int i = 0; i < 2; ++i) {
            int row = i * 64 + srow;
            *(uint4*)(As + row * 64 + ((sc8 ^ (row & 7)) * 8)) = ar[i];
        }
        #pragma unroll
        for (int i = 0; i < NI; ++i) {
            int row = i * 64 + srow;
            *(uint4*)(Bs + row * 64 + ((sc8 ^ (row & 7)) * 8)) = br[i];
        }
        __syncthreads();
        if (t + 1 < nt) {              // prefetch next tile (hides under MFMA)
            int k0 = (t + 1) << 6;
            #pragma unroll
            for (int i = 0; i < 2; ++i) {
                int rg = m0 + i * 64 + srow; if (rg > M - 1) rg = M - 1;
                ar[i] = *(const uint4*)(P.A + (size_t)rg * P.lda + k0 + sc8 * 8);
            }
            #pragma unroll
            for (int i = 0; i < NI; ++i)
                br[i] = *(const uint4*)(P.Bt + (size_t)(n0 + i * 64 + srow) * K + k0 + sc8 * 8);
        }
        #pragma unroll
        for (int kk = 0; kk < 2; ++kk) {
            int g = kk * 4 + (lane >> 4);
            short8 a[4], b[NI];
            #pragma unroll
            for (int mi = 0; mi < 4; ++mi) {
                int row = wr * 64 + mi * 16 + (lane & 15);
                a[mi] = *(const short8*)(As + row * 64 + ((g ^ (row & 7)) * 8));
            }
            #pragma unroll
            for (int ni = 0; ni < NI; ++ni) {
                int row = wc * (BN / 4) + ni * 16 + (lane & 15);
                b[ni] = *(const short8*)(Bs + row * 64 + ((g ^ (row & 7)) * 8));
            }
            #pragma unroll
            for (int mi = 0; mi < 4; ++mi)
                #pragma unroll
                for (int ni = 0; ni < NI; ++ni)
                    acc[mi][ni] = __builtin_amdgcn_mfma_f32_16x16x32_bf16(
                        a[mi], b[ni], acc[mi][ni], 0, 0, 0);
        }
    }

    if (MODE == 0) {
        // two half-tile passes through LDS, full-line uint4 writeback
        unsigned short* stage = smem;  // 64*256 shorts = 32KB
        #pragma unroll
        for (int half = 0; half < 2; ++half) {
            __syncthreads();
            if (wr == half) {
                #pragma unroll
                for (int mi = 0; mi < 4; ++mi)
                    #pragma unroll
                    for (int ni = 0; ni < NI; ++ni) {
                        int colL = wc * 64 + ni * 16 + (lane & 15);
                        #pragma unroll
                        for (int j = 0; j < 4; ++j) {
                            int rel = mi * 16 + ((lane >> 4) << 2) + j;
                            stage[rel * 256 + colL] = f2bf(acc[mi][ni][j]);
                        }
                    }
            }
            __syncthreads();
            #pragma unroll
            for (int p = 0; p < 4; ++p) {
                int idx = p * 512 + tid;
                int r = idx >> 5, c8 = idx & 31;
                int grow = m0 + half * 64 + r;
                if (grow < M)
                    *(uint4*)(P.Cb + (size_t)grow * P.ldcb + n0 + c8 * 8) =
                        *(const uint4*)(stage + r * 256 + c8 * 8);
            }
        }
    }

    if (MODE == 1) {
        // bf16 full-tile stage + write
        __syncthreads();
        #pragma unroll
        for (int mi = 0; mi < 4; ++mi)
            #pragma unroll
            for (int ni = 0; ni < NI; ++ni) {
                int colL = wc * 32 + ni * 16 + (lane & 15);
                float bv = P.bias[colL];
                #pragma unroll
                for (int j = 0; j < 4; ++j) {
                    int rL = wr * 64 + mi * 16 + ((lane >> 4) << 2) + j;
                    smem[rL * 128 + colL] = f2bf(acc[mi][ni][j] + bv);
                }
            }
        __syncthreads();
        #pragma unroll
        for (int p = 0; p < 4; ++p) {
            int idx = p * 512 + tid;
            int r = idx >> 4, c8 = idx & 15;
            int grow = m0 + r;
            if (grow < M)
                *(uint4*)(P.Cb + (size_t)grow * P.ldcb + c8 * 8) =
                    *(const uint4*)(smem + r * 128 + c8 * 8);
        }
        // fp32 in two half-tile passes
        float* stagef = (float*)smem;  // 64*128 floats = 32KB
        #pragma unroll
        for (int half = 0; half < 2; ++half) {
            __syncthreads();
            if (wr == half) {
                #pragma unroll
                for (int mi = 0; mi < 4; ++mi)
                    #pragma unroll
                    for (int ni = 0; ni < NI; ++ni) {
                        int colL = wc * 32 + ni * 16 + (lane & 15);
                        float bv = P.bias[colL];
                        #pragma unroll
                        for (int j = 0; j < 4; ++j) {
                            int rel = mi * 16 + ((lane >> 4) << 2) + j;
                            stagef[rel * 128 + colL] = acc[mi][ni][j] + bv;
                        }
                    }
            }
            __syncthreads();
            #pragma unroll
            for (int p = 0; p < 4; ++p) {
                int idx = p * 512 + tid;
                int r = idx >> 5, c4 = idx & 31;
                int grow = m0 + half * 64 + r;
                if (grow < M)
                    *(float4*)(P.Cf + (size_t)grow * P.ldcf + c4 * 4) =
                        *(const float4*)(stagef + r * 128 + c4 * 4);
            }
        }
    }

    if (MODE == 2) {
        __syncthreads();   // LDS reads of last tile done
        // bias + relu -> swizzled hidden tile in LDS (bf16)
        #pragma unroll
        for (int mi = 0; mi < 4; ++mi)
            #pragma unroll
            for (int ni = 0; ni < NI; ++ni) {
                int colL = wc * 64 + ni * 16 + (lane & 15);
                float bv = P.bias[colL];
                #pragma unroll
                for (int j = 0; j < 4; ++j) {
                    int rL = wr * 64 + mi * 16 + ((lane >> 4) << 2) + j;
                    float x = fmaxf(acc[mi][ni][j] + bv, 0.0f);
                    int c8 = colL >> 3;
                    smem[rL * 256 + ((c8 ^ (rL & 7)) * 8) + (colL & 7)] = f2bf(x);
                }
            }
        __syncthreads();
        // logits: wave wid -> rows wid*16..+15; K=256, 8 MFMA
        f32x4 lacc = {0.f, 0.f, 0.f, 0.f};
        int rL = wid * 16 + (lane & 15);
        #pragma unroll
        for (int k0 = 0; k0 < 256; k0 += 32) {
            int c8 = (k0 >> 3) + (lane >> 4);
            short8 a = *(const short8*)(smem + rL * 256 + ((c8 ^ (rL & 7)) * 8));
            short8 b = *(const short8*)(Wc2t + (lane & 15) * 256 + k0 + (lane >> 4) * 8);
            lacc = __builtin_amdgcn_mfma_f32_16x16x32_bf16(a, b, lacc, 0, 0, 0);
        }
        int colL = lane & 15;
        if (colL < 14) {
            float bb = bc2[colL];
            #pragma unroll
            for (int j = 0; j < 4; ++j) {
                int r = m0 + wid * 16 + (lane >> 4) * 4 + j;
                if (r < M) logits[(size_t)r * 14 + colL] = lacc[j] + bb;
            }
        }
    }
}

// ---- CSR build ----
__global__ void count_deg(const int* __restrict__ dst, int* __restrict__ deg, int E)
{
    int e = blockIdx.x * blockDim.x + threadIdx.x;
    if (e < E) atomicAdd(&deg[dst[e]], 1);
}

// per-block exclusive scan; writes local-exclusive to off, block total to sums
__global__ __launch_bounds__(1024) void scan_part(
    const int* __restrict__ deg, int* __restrict__ off, int* __restrict__ sums, int N)
{
    __shared__ int buf[1024];
    int i = blockIdx.x * 1024 + threadIdx.x;
    int v = (i < N) ? deg[i] : 0;
    buf[threadIdx.x] = v;
    __syncthreads();
    #pragma unroll
    for (int o = 1; o < 1024; o <<= 1) {
        int t = (threadIdx.x >= o) ? buf[threadIdx.x - o] : 0;
        __syncthreads();
        buf[threadIdx.x] += t;
        __syncthreads();
    }
    if (i < N) off[i] = buf[threadIdx.x] - v;
    if (threadIdx.x == 1023) sums[blockIdx.x] = buf[1023];
}

// single wave: exclusive-scan of <=64 block sums; writes total to off[N]
__global__ void scan_sums(int* __restrict__ sums, int* __restrict__ offN, int nb)
{
    int lane = threadIdx.x;
    int v = (lane < nb) ? sums[lane] : 0;
    int incl = v;
    #pragma unroll
    for (int o = 1; o < 64; o <<= 1) {
        int t = __shfl_up(incl, o);
        if (lane >= o) incl += t;
    }
    if (lane < nb) sums[lane] = incl - v;
    if (lane == 63) *offN = incl;
}

__global__ __launch_bounds__(1024) void scan_add(
    const int* __restrict__ sums, int* __restrict__ off,
    int* __restrict__ cursor, int N)
{
    int i = blockIdx.x * 1024 + threadIdx.x;
    if (i < N) {
        int v = off[i] + sums[blockIdx.x];
        off[i] = v;
        cursor[i] = v;
    }
}

__global__ void fill_csr(const int* __restrict__ src, const int* __restrict__ dst,
                         int* __restrict__ cursor, int* __restrict__ csr, int E)
{
    int e = blockIdx.x * blockDim.x + threadIdx.x;
    if (e < E) {
        int p = atomicAdd(&cursor[dst[e]], 1);
        csr[p] = src[e];
    }
}

// ---- conv1 epilogue: h_g1 = relu(mean_nbr(y1.l)+b+y1.r) -> bf16 [N,256] ----
__global__ __launch_bounds__(256) void sage1_gather(
    const unsigned short* __restrict__ y1,
    const int* __restrict__ off, const int* __restrict__ csr,
    const float* __restrict__ b, unsigned short* __restrict__ out, int N)
{
    int lane = threadIdx.x & 63;
    int node = blockIdx.x * 4 + (threadIdx.x >> 6);
    if (node >= N) return;
    int s = off[node], e = off[node + 1];
    float a0 = 0.f, a1 = 0.f, a2 = 0.f, a3 = 0.f;
    for (int p = s; p < e; ++p) {
        int j = csr[p];
        uint2 v = *(const uint2*)(y1 + (size_t)j * 512 + lane * 4);
        a0 += bflo(v.x); a1 += bfhi(v.x); a2 += bflo(v.y); a3 += bfhi(v.y);
    }
    float inv = (e > s) ? 1.0f / (float)(e - s) : 1.0f;
    uint2 rv = *(const uint2*)(y1 + (size_t)node * 512 + 256 + lane * 4);
    float4 bb = ((const float4*)b)[lane];
    ushort4 o;
    o.x = f2bf(fmaxf(a0 * inv + bb.x + bflo(rv.x), 0.0f));
    o.y = f2bf(fmaxf(a1 * inv + bb.y + bfhi(rv.x), 0.0f));
    o.z = f2bf(fmaxf(a2 * inv + bb.z + bflo(rv.y), 0.0f));
    o.w = f2bf(fmaxf(a3 * inv + bb.w + bfhi(rv.y), 0.0f));
    *(ushort4*)(out + (size_t)node * 256 + lane * 4) = o;
}

// ---- conv2 epilogue: h_g = l2norm(mean+b+root) -> bf16 into cls_bf col 384 ----
__global__ __launch_bounds__(256) void sage2_gather_norm(
    const unsigned short* __restrict__ y2,
    const int* __restrict__ off, const int* __restrict__ csr,
    const float* __restrict__ b, unsigned short* __restrict__ outb, int N)
{
    int lane = threadIdx.x & 63;
    int node = blockIdx.x * 4 + (threadIdx.x >> 6);
    if (node >= N) return;
    int s = off[node], e = off[node + 1];
    float a0 = 0.f, a1 = 0.f;
    for (int p = s; p < e; ++p) {
        int j = csr[p];
        unsigned int v = *(const unsigned int*)(y2 + (size_t)j * 256 + lane * 2);
        a0 += bflo(v); a1 += bfhi(v);
    }
    float inv = (e > s) ? 1.0f / (float)(e - s) : 1.0f;
    unsigned int rv = *(const unsigned int*)(y2 + (size_t)node * 256 + 128 + lane * 2);
    float2 bb = ((const float2*)b)[lane];
    float hx = a0 * inv + bb.x + bflo(rv);
    float hy = a1 * inv + bb.y + bfhi(rv);
    float ss = hx * hx + hy * hy;
    #pragma unroll
    for (int o = 32; o; o >>= 1) ss += __shfl_xor(ss, o);
    float sc = 1.0f / fmaxf(sqrtf(ss), 1e-12f);
    ushort2 o2; o2.x = f2bf(hx * sc); o2.y = f2bf(hy * sc);
    *(ushort2*)(outb + (size_t)node * 512 + lane * 2) = o2;
}

extern "C" void kernel_launch(void* const* d_in, const int* in_sizes, int n_in,
                              void* d_out, int out_size, void* d_ws, size_t ws_size,
                              hipStream_t stream)
{
    const float* h_v   = (const float*)d_in[0];
    const float* h_t   = (const float*)d_in[1];
    const float* h_tab = (const float*)d_in[2];
    const int*   eidx  = (const int*)d_in[3];
    const float* W1l = (const float*)d_in[4];
    const float* W1r = (const float*)d_in[5];
    const float* b1g = (const float*)d_in[6];
    const float* W2l = (const float*)d_in[7];
    const float* W2r = (const float*)d_in[8];
    const float* b2g = (const float*)d_in[9];
    const float* Wsh = (const float*)d_in[10];
    const float* bsh = (const float*)d_in[11];
    const float* Wst = (const float*)d_in[12];
    const float* bst = (const float*)d_in[13];
    const float* Wstab = (const float*)d_in[14];
    const float* bstab = (const float*)d_in[15];
    const float* Wc1 = (const float*)d_in[16];
    const float* bc1 = (const float*)d_in[17];
    const float* Wc2 = (const float*)d_in[18];
    const float* bc2 = (const float*)d_in[19];

    const int N = in_sizes[0] / 128;      // 50000
    const int E = in_sizes[3] / 2;        // 500000
    const int* src = eidx;
    const int* dst = eidx + E;

    // ---- workspace layout ----
    int* deg    = (int*)d_ws;
    int* off    = deg + N;
    int* cursor = off + N + 1;
    int* csr    = cursor + N;
    int* sums   = csr + E;                 // [64] block sums for scan
    size_t int_bytes = ((size_t)3 * N + 1 + E + 64) * 4;
    unsigned short* Wt = (unsigned short*)((char*)d_ws + ((int_bytes + 255) & ~(size_t)255));
    const int oW1l = 0;                    // 256*384
    const int oW1r = oW1l + 98304;
    const int oW2l = oW1r + 98304;         // 128*256
    const int oW2r = oW2l + 32768;
    const int oWsh = oW2r + 32768;         // 128*128
    const int oWst = oWsh + 16384;
    const int oWstab = oWst + 16384;
    const int oWc1 = oWstab + 16384;       // 256*512
    const int oWc2t = oWc1 + 131072;       // 16*256 (rows 14,15 zero)
    const int wtotal = oWc2t + 4096;

    unsigned short* Xbf   = Wt + wtotal;                  // [N,384]
    unsigned short* bufY  = Xbf + (size_t)N * 384;        // y1 [N,512] -> cls_bf
    unsigned short* bufH  = bufY + (size_t)N * 512;       // hg1 [N,256]
    unsigned short* bufY2 = bufH + (size_t)N * 256;       // y2 [N,256]

    float* out    = (float*)d_out;
    float* logits = out;
    float* z_sh   = out + (size_t)N * 14;
    float* z_t    = z_sh + (size_t)N * 128;
    float* z_tab  = z_t + (size_t)N * 128;

    const int gx = (N + 127) / 128;  // 391
    const int nb = (N + 1023) / 1024; // 49

    // ---- CSR build ----
    hipMemsetAsync(deg, 0, (size_t)N * 4, stream);
    hipMemsetAsync(Wt + oWc2t, 0, 16 * 256 * 2, stream);
    count_deg<<<(E + 255) / 256, 256, 0, stream>>>(dst, deg, E);
    scan_part<<<nb, 1024, 0, stream>>>(deg, off, sums, N);
    scan_sums<<<1, 64, 0, stream>>>(sums, off + N, nb);
    scan_add<<<nb, 1024, 0, stream>>>(sums, off, cursor, N);
    fill_csr<<<(E + 255) / 256, 256, 0, stream>>>(src, dst, cursor, csr, E);

    // ---- conversions ----
    convert_x<<<(N * 96 + 255) / 256, 256, 0, stream>>>(h_v, h_t, h_tab, Xbf, N * 96);
    WPack p;
    p.w[0] = {W1l, 384, 256, oW1l};     p.w[1] = {W1r, 384, 256, oW1r};
    p.w[2] = {W2l, 256, 128, oW2l};     p.w[3] = {W2r, 256, 128, oW2r};
    p.w[4] = {Wsh, 128, 128, oWsh};     p.w[5] = {Wst, 128, 128, oWst};
    p.w[6] = {Wstab, 128, 128, oWstab}; p.w[7] = {Wc1, 512, 256, oWc1};
    p.w[8] = {Wc2, 256, 14, oWc2t};
    convert_w<<<dim3(128, 9), 256, 0, stream>>>(p, Wt);

    // ---- conv1 fused GEMM: [N,384] x [384, 512(l|r)] -> y1 bf16 ----
    unsigned short* y1 = bufY;
    {
        GemmP3 g{};
        g.q[0] = {Xbf, 384, Wt + oW1l, nullptr, nullptr, 0, y1, 512};
        gemm3<256, 0><<<dim3(gx, 2), 512, 0, stream>>>(g, nullptr, nullptr, nullptr, N, 384);
    }

    // ---- conv1 gather -> h_g1 bf16 [N,256] ----
    sage1_gather<<<(N + 3) / 4, 256, 0, stream>>>(y1, off, csr, b1g, bufH, N);

    // ---- conv2 fused GEMM: [N,256] x [256, 256(l|r)] -> y2 bf16 ----
    {
        GemmP3 g{};
        g.q[0] = {bufH, 256, Wt + oW2l, nullptr, nullptr, 0, bufY2, 256};
        gemm3<256, 0><<<dim3(gx, 1), 512, 0, stream>>>(g, nullptr, nullptr, nullptr, N, 256);
    }

    // ---- conv2 gather + l2norm -> h_g bf16 (cls_bf col 384) ----
    unsigned short* cls_bf = bufY;  // y1 dead
    sage2_gather_norm<<<(N + 3) / 4, 256, 0, stream>>>(bufY2, off, csr, b2g,
        cls_bf + 384, N);

    // ---- 3 projections in one launch: fp32 -> d_out, bf16 -> cls_bf ----
    {
        GemmP3 g{};
        g.q[0] = {cls_bf + 384, 512, Wt + oWsh,   bsh,   z_sh,  128, cls_bf + 0,   512};
        g.q[1] = {Xbf + 128,    384, Wt + oWst,   bst,   z_t,   128, cls_bf + 128, 512};
        g.q[2] = {Xbf + 256,    384, Wt + oWstab, bstab, z_tab, 128, cls_bf + 256, 512};
        gemm3<128, 1><<<dim3(gx, 1, 3), 512, 0, stream>>>(g, nullptr, nullptr, nullptr, N, 128);
    }

    // ---- classifier: [N,512]x[512,256] + relu + fused logits ----
    {
        GemmP3 g{};
        g.q[0] = {cls_bf, 512, Wt + oWc1, bc1, nullptr, 0, nullptr, 0};
        gemm3<256, 2><<<dim3(gx, 1), 512, 0, stream>>>(g, Wt + oWc2t, bc2, logits, N, 512);
    }
}